// Round 11
// baseline (293.990 us; speedup 1.0000x reference)
//
#include <hip/hip_runtime.h>

#define N_NODES 20000
#define N_EDGES 160000
#define H 8
#define DK 32
#define D 256
#define RSQRT_DK 0.17677669529663687f
#define NF ((size_t)N_NODES * D)
#define BKT 48          // bucket stride (max supported degree; Poisson(8) => ~6 sigma margin)
#define ZB 235          // zero blocks (60000/256)
#define XB 5000         // xcvt blocks
#define CB 384          // combine blocks (6 mats x 64)
#define BHB 192         // Bh table build blocks (49152/256)

typedef __attribute__((ext_vector_type(8))) short bfrag;   // 8 bf16 = 4 VGPRs
typedef __attribute__((ext_vector_type(4))) float f32x4;

__device__ __forceinline__ unsigned short f2b(float f) {
    unsigned int u = __builtin_bit_cast(unsigned int, f);
    unsigned int r = (u + 0x7FFFu + ((u >> 16) & 1u)) >> 16;   // RNE
    return (unsigned short)r;
}
__device__ __forceinline__ float b2f(unsigned short s) {
    return __builtin_bit_cast(float, (unsigned int)s << 16);
}
__device__ __forceinline__ float blo(unsigned int u) {
    return __builtin_bit_cast(float, u << 16);
}
__device__ __forceinline__ float bhi(unsigned int u) {
    return __builtin_bit_cast(float, u & 0xFFFF0000u);
}

// ---------------- fused prep ----------------
// GEMM mats: 0 Wq^T, 1 Wk^T, 2 Wv^T, 3..5 (Wq @ BD(CF[ct])^T)^T  (qcf weights)
// Bh table:  Bh[h][f][s*32+d], s<3: msg[s][h][d][f]; s>=3: msg_cau[s-3][h][d][f]*cp[s-3][h*32+f]
__global__ __launch_bounds__(256) void prep_kernel(
    const float* __restrict__ x,
    const float* __restrict__ Wq, const float* __restrict__ Wk, const float* __restrict__ Wv,
    const float* __restrict__ bq, const float* __restrict__ bk, const float* __restrict__ bv,
    const float* __restrict__ cf, const float* __restrict__ msg, const float* __restrict__ msg_cau,
    const float* __restrict__ comb_pri,
    int* __restrict__ counts, unsigned short* __restrict__ Xb,
    unsigned short* __restrict__ Wt_all, float* __restrict__ bias_all,
    unsigned short* __restrict__ Bh)
{
    const int b = blockIdx.x, t = threadIdx.x;
    if (b < ZB) {
        int i = b * 256 + t;
        if (i < 3 * N_NODES) counts[i] = 0;
    } else if (b < ZB + XB) {
        int i = (b - ZB) * 256 + t;          // over NF/4 float4s
        float4 f = reinterpret_cast<const float4*>(x)[i];
        ushort4 u;
        u.x = f2b(f.x); u.y = f2b(f.y); u.z = f2b(f.z); u.w = f2b(f.w);
        reinterpret_cast<ushort4*>(Xb)[i] = u;
    } else if (b < ZB + XB + CB) {
        __shared__ float Wtile[32][33], Mtile[32][33], Ctile[32][33];
        int cb = b - ZB - XB;
        int m = cb >> 6, h0 = (cb >> 3) & 7, k0 = (cb & 7) * 32;
        int tx = t & 31, ty = t >> 5;
        const float* W = (m == 0) ? Wq : (m == 1) ? Wk : (m == 2) ? Wv : Wq;
        #pragma unroll
        for (int it = 0; it < 4; ++it) {
            int kk = ty + it * 8;
            Wtile[kk][tx] = W[(size_t)(k0 + kk) * 256 + h0 * 32 + tx];
            if (m >= 3)   // Mtile[a][b] = CF[ct][h0][b][a]
                Mtile[kk][tx] = cf[(size_t)(((m - 3) * 8 + h0) * 32 + tx) * 32 + kk];
        }
        __syncthreads();
        #pragma unroll
        for (int it = 0; it < 4; ++it) {
            int kk = ty + it * 8;
            if (m < 3) {
                Ctile[kk][tx] = Wtile[kk][tx];
            } else {
                float a = 0.f;
                #pragma unroll
                for (int d = 0; d < 32; ++d)
                    a += Wtile[kk][d] * Mtile[d][tx];
                Ctile[kk][tx] = a;
            }
        }
        __syncthreads();
        unsigned short* Wm = Wt_all + (size_t)m * 65536;
        #pragma unroll
        for (int it = 0; it < 4; ++it) {
            int cc = ty + it * 8;
            Wm[(size_t)(h0 * 32 + cc) * 256 + k0 + tx] = f2b(Ctile[tx][cc]);
        }
    } else if (b < ZB + XB + CB + 6) {
        int m = b - ZB - XB - CB;            // 0..5
        int c = t, h = c >> 5, d = c & 31;
        float r;
        if (m == 0) r = bq[c];
        else if (m == 1) r = bk[c];
        else if (m == 2) r = bv[c];
        else {
            float a = 0.f;
            #pragma unroll
            for (int f = 0; f < 32; ++f)
                a += bq[h * 32 + f] * cf[(size_t)(((m - 3) * 8 + h) * 32 + d) * 32 + f];
            r = a;
        }
        bias_all[m * 256 + c] = r;
    } else {
        int idx = (b - ZB - XB - CB - 6) * 256 + t;   // over 8*32*192
        int h = idx / 6144;
        int rem = idx - h * 6144;
        int f = rem / 192;
        int k = rem - f * 192;
        int s = k >> 5, d = k & 31;
        float v;
        if (s < 3)
            v = msg[(size_t)((s * 8 + h) * 32 + d) * 32 + f];
        else
            v = msg_cau[(size_t)(((s - 3) * 8 + h) * 32 + d) * 32 + f]
              * comb_pri[(s - 3) * 256 + h * 32 + f];
        Bh[idx] = f2b(v);
    }
}

// ---------------- GEMM + scatter in one launch ----------------
// grid (157, 2, 7). z<6: batched bf16 MFMA GEMM out[mat] = X @ Wt[mat]^T + bias[mat]
//   mat0->qb; mat1->kv even; mat2->kv odd; mat3..5->qcf_all.
// z==6: edge scatter into fixed-stride buckets (seg = dst*3 + etype), atomic counting.
__global__ __launch_bounds__(256) void gemm_scatter_kernel(
    const unsigned short* __restrict__ Xb, const unsigned short* __restrict__ Wt_all,
    const float* __restrict__ bias_all,
    const int* __restrict__ src, const int* __restrict__ dst, const int* __restrict__ cau_type,
    unsigned short* __restrict__ qb, unsigned short* __restrict__ kv,
    unsigned short* __restrict__ qcf_all,
    int* __restrict__ counts, int* __restrict__ buckets)
{
    __shared__ unsigned short As[128][72];
    __shared__ unsigned short Bs[128][72];
    if (blockIdx.z == 6) {
        int base = (blockIdx.y * 157 + blockIdx.x) * 256 + threadIdx.x;  // 0..80383
        for (int i = base; i < 3 * N_EDGES; i += 157 * 2 * 256) {
            int e = i / N_EDGES;
            int d = dst[i], s = src[i];
            int ct = cau_type[s];
            int seg = d * 3 + e;
            int p = atomicAdd(&counts[seg], 1);
            if (p < BKT) buckets[(size_t)seg * BKT + p] = s | (ct << 24);
        }
        return;
    }
    const int t = threadIdx.x;
    const int wv = t >> 6, lane = t & 63;
    const int l15 = lane & 15, q4 = lane >> 4;
    const int wr = wv >> 1, wc = wv & 1;
    const int m0 = blockIdx.x * 128;
    const int n0 = blockIdx.y * 128;
    const int mat = blockIdx.z;
    const unsigned short* Wm = Wt_all + (size_t)mat * 65536;
    const float* bias = bias_all + mat * 256;

    f32x4 acc[4][4] = {};
    for (int kk = 0; kk < 256; kk += 64) {
        #pragma unroll
        for (int it = 0; it < 4; ++it) {
            int lin = t + it * 256;
            int row = lin >> 3, c8 = (lin & 7) * 8;
            int node = m0 + row;
            bfrag a = {};
            if (node < N_NODES)
                a = *reinterpret_cast<const bfrag*>(Xb + (size_t)node * 256 + kk + c8);
            *reinterpret_cast<bfrag*>(&As[row][c8]) = a;
            bfrag bfr = *reinterpret_cast<const bfrag*>(Wm + (size_t)(n0 + row) * 256 + kk + c8);
            *reinterpret_cast<bfrag*>(&Bs[row][c8]) = bfr;
        }
        __syncthreads();
        #pragma unroll
        for (int ks = 0; ks < 2; ++ks) {
            bfrag af[4], bf[4];
            #pragma unroll
            for (int i = 0; i < 4; ++i) {
                af[i] = *reinterpret_cast<const bfrag*>(&As[wr * 64 + i * 16 + l15][ks * 32 + q4 * 8]);
                bf[i] = *reinterpret_cast<const bfrag*>(&Bs[wc * 64 + i * 16 + l15][ks * 32 + q4 * 8]);
            }
            #pragma unroll
            for (int mi = 0; mi < 4; ++mi)
                #pragma unroll
                for (int ni = 0; ni < 4; ++ni)
                    acc[mi][ni] = __builtin_amdgcn_mfma_f32_16x16x32_bf16(
                        bf[ni], af[mi], acc[mi][ni], 0, 0, 0);
        }
        __syncthreads();
    }
    #pragma unroll
    for (int mi = 0; mi < 4; ++mi) {
        int node = m0 + wr * 64 + mi * 16 + l15;
        if (node >= N_NODES) continue;
        #pragma unroll
        for (int ni = 0; ni < 4; ++ni) {
            int col = n0 + wc * 64 + ni * 16 + q4 * 4;
            ushort4 u;
            u.x = f2b(acc[mi][ni][0] + bias[col + 0]);
            u.y = f2b(acc[mi][ni][1] + bias[col + 1]);
            u.z = f2b(acc[mi][ni][2] + bias[col + 2]);
            u.w = f2b(acc[mi][ni][3] + bias[col + 3]);
            if (mat == 0)
                *reinterpret_cast<ushort4*>(&qb[(size_t)node * 256 + col]) = u;
            else if (mat == 1)
                *reinterpret_cast<ushort4*>(&kv[(size_t)node * 512 + col * 2]) = u;
            else if (mat == 2)
                *reinterpret_cast<ushort4*>(&kv[(size_t)node * 512 + col * 2 + 4]) = u;
            else
                *reinterpret_cast<ushort4*>(&qcf_all[(size_t)(mat - 3) * NF + (size_t)node * 256 + col]) = u;
        }
    }
}

// ---------------- attn: one block per node (3 waves = 3 etypes) ----------------
// Bucket list held in registers (one lane-load + shuffles); depth-3 gather pipeline.
// Writes per-head aggregates AVh[h][n][slab][32] bf16, slabs: 0..2 = av_e, 3..5 = acv_e(+te)
__global__ __launch_bounds__(192) void attn_kernel(
    const unsigned short* __restrict__ qb, const unsigned short* __restrict__ qcf_all,
    const unsigned short* __restrict__ kv,
    const int* __restrict__ buckets, const int* __restrict__ counts,
    const float* __restrict__ pri, const float* __restrict__ pri_cau,
    const float* __restrict__ te, unsigned short* __restrict__ AVh)
{
    const int n = blockIdx.x;
    const int e = threadIdx.x >> 6, lane = threadIdx.x & 63;
    const int h = lane >> 3;
    const int seg = n * 3 + e;

    int cnt = counts[seg];
    cnt = (cnt > BKT) ? BKT : cnt;
    const int* bk = buckets + (size_t)seg * BKT;

    // whole bucket list -> registers: one coalesced load, indices via shuffle
    unsigned spv = (lane < BKT) ? (unsigned)bk[lane] : 0u;

    const float pe  = pri    [e * H + h] * RSQRT_DK;
    const float pce = pri_cau[e * H + h] * RSQRT_DK;

    ushort4 qu = *reinterpret_cast<const ushort4*>(qb + (size_t)n * 256 + lane * 4);
    float4 qv = make_float4(b2f(qu.x), b2f(qu.y), b2f(qu.z), b2f(qu.w));
    float4 qc[3];
    #pragma unroll
    for (int c = 0; c < 3; ++c) {
        ushort4 cu = *reinterpret_cast<const ushort4*>(qcf_all + (size_t)c * NF + (size_t)n * 256 + lane * 4);
        qc[c] = make_float4(b2f(cu.x), b2f(cu.y), b2f(cu.z), b2f(cu.w));
    }

    float den = 0.f, cden = 0.f;
    float4 num  = make_float4(0.f, 0.f, 0.f, 0.f);
    float4 cnum = make_float4(0.f, 0.f, 0.f, 0.f);

#define LD(sp) (*reinterpret_cast<const uint4*>(kv + (size_t)((sp) & 0xFFFFFF) * 512 + lane * 8))
#define ACC_EDGE(sp, g) do {                                                        \
        int ct_ = (int)((sp) >> 24);                                                \
        float4 qs = (ct_ == 0) ? qc[0] : (ct_ == 1) ? qc[1] : qc[2];                \
        float k0 = blo(g.x), k1 = bhi(g.x), k2 = blo(g.y), k3 = bhi(g.y);           \
        float dk = qv.x * k0 + qv.y * k1 + qv.z * k2 + qv.w * k3;                   \
        float dm = qs.x * k0 + qs.y * k1 + qs.z * k2 + qs.w * k3;                   \
        dk += __shfl_xor(dk, 1, 64); dm += __shfl_xor(dm, 1, 64);                   \
        dk += __shfl_xor(dk, 2, 64); dm += __shfl_xor(dm, 2, 64);                   \
        dk += __shfl_xor(dk, 4, 64); dm += __shfl_xor(dm, 4, 64);                   \
        float wg = __expf(dk * pe);                                                 \
        float cw = __expf(dm * pce);                                                \
        den += wg; cden += cw;                                                      \
        num.x  += wg * blo(g.z); num.y  += wg * bhi(g.z);                           \
        num.z  += wg * blo(g.w); num.w  += wg * bhi(g.w);                           \
        cnum.x += cw * blo(g.z); cnum.y += cw * bhi(g.z);                           \
        cnum.z += cw * blo(g.w); cnum.w += cw * bhi(g.w);                           \
    } while (0)

    float4 av  = make_float4(0.f, 0.f, 0.f, 0.f);
    float4 acv = make_float4(0.f, 0.f, 0.f, 0.f);
    if (cnt > 0) {
        int last = cnt - 1;
        unsigned sp0 = __shfl(spv, 0, 64);
        unsigned sp1 = __shfl(spv, (1 < last) ? 1 : last, 64);
        uint4 g0 = LD(sp0);
        uint4 g1 = LD(sp1);
        for (int i = 0; i < last; ++i) {
            int i2 = i + 2;
            i2 = (i2 < last) ? i2 : last;
            unsigned sp2 = __shfl(spv, i2, 64);
            uint4 g2 = LD(sp2);
            ACC_EDGE(sp0, g0);
            sp0 = sp1; g0 = g1; sp1 = sp2; g1 = g2;
        }
        ACC_EDGE(sp0, g0);
        float4 te4 = *reinterpret_cast<const float4*>(te + lane * 4);
        float rd = 1.f / den, rc = 1.f / cden;
        av.x = num.x * rd;  av.y = num.y * rd;  av.z = num.z * rd;  av.w = num.w * rd;
        acv.x = cnum.x * rc + te4.x; acv.y = cnum.y * rc + te4.y;
        acv.z = cnum.z * rc + te4.z; acv.w = cnum.w * rc + te4.w;
    }
#undef ACC_EDGE
#undef LD

    size_t base = ((size_t)h * N_NODES + n) * 6;
    ushort4 ua, uc;
    ua.x = f2b(av.x);  ua.y = f2b(av.y);  ua.z = f2b(av.z);  ua.w = f2b(av.w);
    uc.x = f2b(acv.x); uc.y = f2b(acv.y); uc.z = f2b(acv.z); uc.w = f2b(acv.w);
    *reinterpret_cast<ushort4*>(&AVh[(base + e) * 32 + (lane & 7) * 4]) = ua;
    *reinterpret_cast<ushort4*>(&AVh[(base + 3 + e) * 32 + (lane & 7) * 4]) = uc;
}

// ---------------- final: per-head MFMA GEMM [20000 x 32] = AVh[h] (20000x192) @ Bh[h] ----------------
__global__ __launch_bounds__(256) void final_kernel(
    const unsigned short* __restrict__ AVh, const unsigned short* __restrict__ Bh,
    float* __restrict__ out)
{
    __shared__ unsigned short As[128][200];
    __shared__ unsigned short Bs[32][200];
    const int t = threadIdx.x;
    const int w = t >> 6, lane = t & 63;
    const int l15 = lane & 15, q4 = lane >> 4;
    const int m0 = blockIdx.x * 128;
    const int h = blockIdx.y;

    #pragma unroll
    for (int it = 0; it < 12; ++it) {
        int lin = t + it * 256;           // 3072 chunks of 8 shorts
        int row = lin / 24, c8 = (lin - row * 24) * 8;
        int node = m0 + row;
        bfrag a = {};
        if (node < N_NODES)
            a = *reinterpret_cast<const bfrag*>(AVh + ((size_t)h * N_NODES + node) * 192 + c8);
        *reinterpret_cast<bfrag*>(&As[row][c8]) = a;
    }
    #pragma unroll
    for (int it = 0; it < 3; ++it) {
        int lin = t + it * 256;           // 768 chunks
        int row = lin / 24, c8 = (lin - row * 24) * 8;
        bfrag bfr = *reinterpret_cast<const bfrag*>(Bh + (size_t)(h * 32 + row) * 192 + c8);
        *reinterpret_cast<bfrag*>(&Bs[row][c8]) = bfr;
    }
    __syncthreads();

    f32x4 acc[2][2] = {};
    #pragma unroll
    for (int kk = 0; kk < 6; ++kk) {
        bfrag af[2], bf[2];
        #pragma unroll
        for (int i = 0; i < 2; ++i) {
            af[i] = *reinterpret_cast<const bfrag*>(&As[w * 32 + i * 16 + l15][kk * 32 + q4 * 8]);
            bf[i] = *reinterpret_cast<const bfrag*>(&Bs[i * 16 + l15][kk * 32 + q4 * 8]);
        }
        #pragma unroll
        for (int mi = 0; mi < 2; ++mi)
            #pragma unroll
            for (int ni = 0; ni < 2; ++ni)
                acc[mi][ni] = __builtin_amdgcn_mfma_f32_16x16x32_bf16(
                    bf[ni], af[mi], acc[mi][ni], 0, 0, 0);
    }
    #pragma unroll
    for (int mi = 0; mi < 2; ++mi) {
        int node = m0 + w * 32 + mi * 16 + l15;
        if (node >= N_NODES) continue;
        #pragma unroll
        for (int ni = 0; ni < 2; ++ni) {
            int col = h * 32 + ni * 16 + q4 * 4;
            float4 r;
            r.x = fmaxf(acc[mi][ni][0] * (1.f / 3.f), 0.f);
            r.y = fmaxf(acc[mi][ni][1] * (1.f / 3.f), 0.f);
            r.z = fmaxf(acc[mi][ni][2] * (1.f / 3.f), 0.f);
            r.w = fmaxf(acc[mi][ni][3] * (1.f / 3.f), 0.f);
            *reinterpret_cast<float4*>(&out[(size_t)node * 256 + col]) = r;
        }
    }
}

extern "C" void kernel_launch(void* const* d_in, const int* in_sizes, int n_in,
                              void* d_out, int out_size, void* d_ws, size_t ws_size,
                              hipStream_t stream) {
    const float* x        = (const float*)d_in[0];
    const float* Wk       = (const float*)d_in[1];
    const float* bk       = (const float*)d_in[2];
    const float* Wq       = (const float*)d_in[3];
    const float* bq       = (const float*)d_in[4];
    const float* Wv       = (const float*)d_in[5];
    const float* bv       = (const float*)d_in[6];
    const float* pri      = (const float*)d_in[7];
    const float* msg      = (const float*)d_in[8];
    const float* pri_cau  = (const float*)d_in[9];
    const float* msg_cau  = (const float*)d_in[10];
    const float* comb_pri = (const float*)d_in[11];
    const float* cau_filt = (const float*)d_in[12];
    const float* time_emb = (const float*)d_in[13];
    const int*   cau_type = (const int*)d_in[14];
    const int*   src      = (const int*)d_in[15];
    const int*   dst      = (const int*)d_in[16];
    float* out = (float*)d_out;

    unsigned short* qb      = (unsigned short*)d_ws;             // NF
    unsigned short* kv      = qb + NF;                           // 2*NF (k|v interleaved 4-chunks)
    unsigned short* qcf_all = kv + 2 * NF;                       // 3*NF
    unsigned short* Xb      = qcf_all + 3 * NF;                  // NF
    unsigned short* AVh     = Xb + NF;                           // 8*20000*192
    unsigned short* Wt_all  = AVh + (size_t)8 * N_NODES * 192;   // 6*65536
    unsigned short* Bh      = Wt_all + 6 * 65536;                // 8*32*192
    float* bias_all         = (float*)(Bh + 8 * 32 * 192);       // 6*256
    int* counts  = (int*)(bias_all + 6 * 256);                   // 60000
    int* buckets = counts + 3 * N_NODES;                         // 60000*BKT
    size_t need = (size_t)((char*)(buckets + (size_t)3 * N_NODES * BKT) - (char*)d_ws);
    if (ws_size < need) return;

    prep_kernel<<<dim3(ZB + XB + CB + 6 + BHB), dim3(256), 0, stream>>>(
        x, Wq, Wk, Wv, bq, bk, bv, cau_filt, msg, msg_cau, comb_pri,
        counts, Xb, Wt_all, bias_all, Bh);
    gemm_scatter_kernel<<<dim3((N_NODES + 127) / 128, 2, 7), dim3(256), 0, stream>>>(
        Xb, Wt_all, bias_all, src, dst, cau_type, qb, kv, qcf_all, counts, buckets);
    attn_kernel<<<dim3(N_NODES), dim3(192), 0, stream>>>(
        qb, qcf_all, kv, buckets, counts, pri, pri_cau, time_emb, AVh);
    final_kernel<<<dim3(157, 8), dim3(256), 0, stream>>>(AVh, Bh, out);
}

// Round 12
// 272.642 us; speedup vs baseline: 1.0783x; 1.0783x over previous
//
#include <hip/hip_runtime.h>

#define N_NODES 20000
#define N_EDGES 160000
#define H 8
#define DK 32
#define D 256
#define RSQRT_DK 0.17677669529663687f
#define NF ((size_t)N_NODES * D)
#define BKT 48          // bucket stride (max supported degree; Poisson(8) => ~6 sigma margin)
#define ZB 235          // zero blocks (60000/256)
#define XB 5000         // xcvt blocks
#define CB 384          // combine blocks (6 mats x 64)
#define BHB 192         // Bh table build blocks (49152/256)

typedef __attribute__((ext_vector_type(8))) short bfrag;   // 8 bf16 = 4 VGPRs
typedef __attribute__((ext_vector_type(4))) float f32x4;

__device__ __forceinline__ unsigned short f2b(float f) {
    unsigned int u = __builtin_bit_cast(unsigned int, f);
    unsigned int r = (u + 0x7FFFu + ((u >> 16) & 1u)) >> 16;   // RNE
    return (unsigned short)r;
}
__device__ __forceinline__ float b2f(unsigned short s) {
    return __builtin_bit_cast(float, (unsigned int)s << 16);
}
__device__ __forceinline__ float blo(unsigned int u) {
    return __builtin_bit_cast(float, u << 16);
}
__device__ __forceinline__ float bhi(unsigned int u) {
    return __builtin_bit_cast(float, u & 0xFFFF0000u);
}

// async global->LDS: dest = lds_base + lane*16 (wave-uniform base), 16B per lane
#define GLL(g, l) __builtin_amdgcn_global_load_lds(                                  \
    (const __attribute__((address_space(1))) void*)(g),                              \
    (__attribute__((address_space(3))) void*)(l), 16, 0, 0)

// ---------------- fused prep ----------------
// GEMM mats: 0 Wq^T, 1 Wk^T, 2 Wv^T, 3..5 (Wq @ BD(CF[ct])^T)^T  (qcf weights)
// Bh table:  Bh[h][f][s*32+d], s<3: msg[s][h][d][f]; s>=3: msg_cau[s-3][h][d][f]*cp[s-3][h*32+f]
__global__ __launch_bounds__(256) void prep_kernel(
    const float* __restrict__ x,
    const float* __restrict__ Wq, const float* __restrict__ Wk, const float* __restrict__ Wv,
    const float* __restrict__ bq, const float* __restrict__ bk, const float* __restrict__ bv,
    const float* __restrict__ cf, const float* __restrict__ msg, const float* __restrict__ msg_cau,
    const float* __restrict__ comb_pri,
    int* __restrict__ counts, unsigned short* __restrict__ Xb,
    unsigned short* __restrict__ Wt_all, float* __restrict__ bias_all,
    unsigned short* __restrict__ Bh)
{
    const int b = blockIdx.x, t = threadIdx.x;
    if (b < ZB) {
        int i = b * 256 + t;
        if (i < 3 * N_NODES) counts[i] = 0;
    } else if (b < ZB + XB) {
        int i = (b - ZB) * 256 + t;          // over NF/4 float4s
        float4 f = reinterpret_cast<const float4*>(x)[i];
        ushort4 u;
        u.x = f2b(f.x); u.y = f2b(f.y); u.z = f2b(f.z); u.w = f2b(f.w);
        reinterpret_cast<ushort4*>(Xb)[i] = u;
    } else if (b < ZB + XB + CB) {
        __shared__ float Wtile[32][33], Mtile[32][33], Ctile[32][33];
        int cb = b - ZB - XB;
        int m = cb >> 6, h0 = (cb >> 3) & 7, k0 = (cb & 7) * 32;
        int tx = t & 31, ty = t >> 5;
        const float* W = (m == 0) ? Wq : (m == 1) ? Wk : (m == 2) ? Wv : Wq;
        #pragma unroll
        for (int it = 0; it < 4; ++it) {
            int kk = ty + it * 8;
            Wtile[kk][tx] = W[(size_t)(k0 + kk) * 256 + h0 * 32 + tx];
            if (m >= 3)   // Mtile[a][b] = CF[ct][h0][b][a]
                Mtile[kk][tx] = cf[(size_t)(((m - 3) * 8 + h0) * 32 + tx) * 32 + kk];
        }
        __syncthreads();
        #pragma unroll
        for (int it = 0; it < 4; ++it) {
            int kk = ty + it * 8;
            if (m < 3) {
                Ctile[kk][tx] = Wtile[kk][tx];
            } else {
                float a = 0.f;
                #pragma unroll
                for (int d = 0; d < 32; ++d)
                    a += Wtile[kk][d] * Mtile[d][tx];
                Ctile[kk][tx] = a;
            }
        }
        __syncthreads();
        unsigned short* Wm = Wt_all + (size_t)m * 65536;
        #pragma unroll
        for (int it = 0; it < 4; ++it) {
            int cc = ty + it * 8;
            Wm[(size_t)(h0 * 32 + cc) * 256 + k0 + tx] = f2b(Ctile[tx][cc]);
        }
    } else if (b < ZB + XB + CB + 6) {
        int m = b - ZB - XB - CB;            // 0..5
        int c = t, h = c >> 5, d = c & 31;
        float r;
        if (m == 0) r = bq[c];
        else if (m == 1) r = bk[c];
        else if (m == 2) r = bv[c];
        else {
            float a = 0.f;
            #pragma unroll
            for (int f = 0; f < 32; ++f)
                a += bq[h * 32 + f] * cf[(size_t)(((m - 3) * 8 + h) * 32 + d) * 32 + f];
            r = a;
        }
        bias_all[m * 256 + c] = r;
    } else {
        int idx = (b - ZB - XB - CB - 6) * 256 + t;   // over 8*32*192
        int h = idx / 6144;
        int rem = idx - h * 6144;
        int f = rem / 192;
        int k = rem - f * 192;
        int s = k >> 5, d = k & 31;
        float v;
        if (s < 3)
            v = msg[(size_t)((s * 8 + h) * 32 + d) * 32 + f];
        else
            v = msg_cau[(size_t)(((s - 3) * 8 + h) * 32 + d) * 32 + f]
              * comb_pri[(s - 3) * 256 + h * 32 + f];
        Bh[idx] = f2b(v);
    }
}

// ---------------- GEMM + scatter in one launch ----------------
// grid (157, 2, 7). z<6: batched bf16 MFMA GEMM out[mat] = X @ Wt[mat]^T + bias[mat]
//   mat0->qb; mat1->kv even; mat2->kv odd; mat3..5->qcf_all.
// Staging via global_load_lds (16B/lane) with XOR-swizzled LDS (colblock ^= row&7):
//   conflict-free frag reads without padding. OOB rows read in-workspace garbage that
//   only lands in discarded C rows.
// z==6: edge scatter into fixed-stride buckets (seg = dst*3 + etype), atomic counting.
__global__ __launch_bounds__(256) void gemm_scatter_kernel(
    const unsigned short* __restrict__ Xb, const unsigned short* __restrict__ Wt_all,
    const float* __restrict__ bias_all,
    const int* __restrict__ src, const int* __restrict__ dst, const int* __restrict__ cau_type,
    unsigned short* __restrict__ qb, unsigned short* __restrict__ kv,
    unsigned short* __restrict__ qcf_all,
    int* __restrict__ counts, int* __restrict__ buckets)
{
    __shared__ unsigned short As[128 * 64];   // swizzled, 16 KB
    __shared__ unsigned short Bs[128 * 64];
    if (blockIdx.z == 6) {
        int base = (blockIdx.y * 157 + blockIdx.x) * 256 + threadIdx.x;  // 0..80383
        for (int i = base; i < 3 * N_EDGES; i += 157 * 2 * 256) {
            int e = i / N_EDGES;
            int d = dst[i], s = src[i];
            int ct = cau_type[s];
            int seg = d * 3 + e;
            int p = atomicAdd(&counts[seg], 1);
            if (p < BKT) buckets[(size_t)seg * BKT + p] = s | (ct << 24);
        }
        return;
    }
    const int t = threadIdx.x;
    const int wv = t >> 6, lane = t & 63;
    const int l15 = lane & 15, q4 = lane >> 4;
    const int wr = wv >> 1, wc = wv & 1;
    const int m0 = blockIdx.x * 128;
    const int n0 = blockIdx.y * 128;
    const int mat = blockIdx.z;
    const unsigned short* Wm = Wt_all + (size_t)mat * 65536;
    const float* bias = bias_all + mat * 256;

    // per-lane staging source geometry (constant over K loop)
    const int srow = (lane >> 3);                       // row-within-8-row chunk
    const int scb  = (lane & 7) ^ srow;                 // swizzled source colblock (8 shorts)

    f32x4 acc[4][4] = {};
    for (int kk = 0; kk < 256; kk += 64) {
        #pragma unroll
        for (int j = 0; j < 4; ++j) {
            int c  = wv * 4 + j;                        // 8-row chunk id, wave-uniform
            int ra = c * 8 + srow;                      // row in tile
            GLL(Xb + (size_t)(m0 + ra) * 256 + kk + scb * 8, As + c * 512);
            GLL(Wm + (size_t)(n0 + ra) * 256 + kk + scb * 8, Bs + c * 512);
        }
        __syncthreads();
        #pragma unroll
        for (int ks = 0; ks < 2; ++ks) {
            bfrag af[4], bf[4];
            #pragma unroll
            for (int i = 0; i < 4; ++i) {
                int ar = wr * 64 + i * 16 + l15;
                int br = wc * 64 + i * 16 + l15;
                int cb = (ks * 4 + q4) ^ (l15 & 7);
                af[i] = *reinterpret_cast<const bfrag*>(As + ar * 64 + cb * 8);
                bf[i] = *reinterpret_cast<const bfrag*>(Bs + br * 64 + cb * 8);
            }
            #pragma unroll
            for (int mi = 0; mi < 4; ++mi)
                #pragma unroll
                for (int ni = 0; ni < 4; ++ni)
                    acc[mi][ni] = __builtin_amdgcn_mfma_f32_16x16x32_bf16(
                        bf[ni], af[mi], acc[mi][ni], 0, 0, 0);
        }
        __syncthreads();
    }
    #pragma unroll
    for (int mi = 0; mi < 4; ++mi) {
        int node = m0 + wr * 64 + mi * 16 + l15;
        if (node >= N_NODES) continue;
        #pragma unroll
        for (int ni = 0; ni < 4; ++ni) {
            int col = n0 + wc * 64 + ni * 16 + q4 * 4;
            ushort4 u;
            u.x = f2b(acc[mi][ni][0] + bias[col + 0]);
            u.y = f2b(acc[mi][ni][1] + bias[col + 1]);
            u.z = f2b(acc[mi][ni][2] + bias[col + 2]);
            u.w = f2b(acc[mi][ni][3] + bias[col + 3]);
            if (mat == 0)
                *reinterpret_cast<ushort4*>(&qb[(size_t)node * 256 + col]) = u;
            else if (mat == 1)
                *reinterpret_cast<ushort4*>(&kv[(size_t)node * 512 + col * 2]) = u;
            else if (mat == 2)
                *reinterpret_cast<ushort4*>(&kv[(size_t)node * 512 + col * 2 + 4]) = u;
            else
                *reinterpret_cast<ushort4*>(&qcf_all[(size_t)(mat - 3) * NF + (size_t)node * 256 + col]) = u;
        }
    }
}

// ---------------- attn: one block per node (3 waves = 3 etypes); R7 rotation loop ----------------
// Writes per-head aggregates AVh[h][n][slab][32] bf16, slabs: 0..2 = av_e, 3..5 = acv_e(+te)
__global__ __launch_bounds__(192) void attn_kernel(
    const unsigned short* __restrict__ qb, const unsigned short* __restrict__ qcf_all,
    const unsigned short* __restrict__ kv,
    const int* __restrict__ buckets, const int* __restrict__ counts,
    const float* __restrict__ pri, const float* __restrict__ pri_cau,
    const float* __restrict__ te, unsigned short* __restrict__ AVh)
{
    const int n = blockIdx.x;
    const int e = threadIdx.x >> 6, lane = threadIdx.x & 63;
    const int h = lane >> 3;
    const int seg = n * 3 + e;

    int cnt = counts[seg];
    cnt = (cnt > BKT) ? BKT : cnt;
    const int* bk = buckets + (size_t)seg * BKT;

    const float pe  = pri    [e * H + h] * RSQRT_DK;
    const float pce = pri_cau[e * H + h] * RSQRT_DK;

    ushort4 qu = *reinterpret_cast<const ushort4*>(qb + (size_t)n * 256 + lane * 4);
    float4 qv = make_float4(b2f(qu.x), b2f(qu.y), b2f(qu.z), b2f(qu.w));
    float4 qc[3];
    #pragma unroll
    for (int c = 0; c < 3; ++c) {
        ushort4 cu = *reinterpret_cast<const ushort4*>(qcf_all + (size_t)c * NF + (size_t)n * 256 + lane * 4);
        qc[c] = make_float4(b2f(cu.x), b2f(cu.y), b2f(cu.z), b2f(cu.w));
    }

    float den = 0.f, cden = 0.f;
    float4 num  = make_float4(0.f, 0.f, 0.f, 0.f);
    float4 cnum = make_float4(0.f, 0.f, 0.f, 0.f);

#define ACC_EDGE(sp, g) do {                                                        \
        int ct_ = (int)((sp) >> 24);                                                \
        float4 qs = (ct_ == 0) ? qc[0] : (ct_ == 1) ? qc[1] : qc[2];                \
        float k0 = blo(g.x), k1 = bhi(g.x), k2 = blo(g.y), k3 = bhi(g.y);           \
        float dk = qv.x * k0 + qv.y * k1 + qv.z * k2 + qv.w * k3;                   \
        float dm = qs.x * k0 + qs.y * k1 + qs.z * k2 + qs.w * k3;                   \
        dk += __shfl_xor(dk, 1, 64); dm += __shfl_xor(dm, 1, 64);                   \
        dk += __shfl_xor(dk, 2, 64); dm += __shfl_xor(dm, 2, 64);                   \
        dk += __shfl_xor(dk, 4, 64); dm += __shfl_xor(dm, 4, 64);                   \
        float wg = __expf(dk * pe);                                                 \
        float cw = __expf(dm * pce);                                                \
        den += wg; cden += cw;                                                      \
        num.x  += wg * blo(g.z); num.y  += wg * bhi(g.z);                           \
        num.z  += wg * blo(g.w); num.w  += wg * bhi(g.w);                           \
        cnum.x += cw * blo(g.z); cnum.y += cw * bhi(g.z);                           \
        cnum.z += cw * blo(g.w); cnum.w += cw * bhi(g.w);                           \
    } while (0)

    float4 av  = make_float4(0.f, 0.f, 0.f, 0.f);
    float4 acv = make_float4(0.f, 0.f, 0.f, 0.f);
    if (cnt > 0) {
        unsigned spA = (unsigned)bk[0];
        unsigned spB = (unsigned)bk[(cnt > 1) ? 1 : 0];
        uint4 gA = *reinterpret_cast<const uint4*>(kv + (size_t)(spA & 0xFFFFFF) * 512 + lane * 8);
        for (int i = 1; i < cnt; ++i) {
            int iC = i + 1;
            iC = (iC < cnt) ? iC : (cnt - 1);
            unsigned spC = (unsigned)bk[iC];
            uint4 gB = *reinterpret_cast<const uint4*>(kv + (size_t)(spB & 0xFFFFFF) * 512 + lane * 8);
            ACC_EDGE(spA, gA);
            spA = spB; gA = gB; spB = spC;
        }
        ACC_EDGE(spA, gA);
        float4 te4 = *reinterpret_cast<const float4*>(te + lane * 4);
        float rd = 1.f / den, rc = 1.f / cden;
        av.x = num.x * rd;  av.y = num.y * rd;  av.z = num.z * rd;  av.w = num.w * rd;
        acv.x = cnum.x * rc + te4.x; acv.y = cnum.y * rc + te4.y;
        acv.z = cnum.z * rc + te4.z; acv.w = cnum.w * rc + te4.w;
    }
#undef ACC_EDGE

    size_t base = ((size_t)h * N_NODES + n) * 6;
    ushort4 ua, uc;
    ua.x = f2b(av.x);  ua.y = f2b(av.y);  ua.z = f2b(av.z);  ua.w = f2b(av.w);
    uc.x = f2b(acv.x); uc.y = f2b(acv.y); uc.z = f2b(acv.z); uc.w = f2b(acv.w);
    *reinterpret_cast<ushort4*>(&AVh[(base + e) * 32 + (lane & 7) * 4]) = ua;
    *reinterpret_cast<ushort4*>(&AVh[(base + 3 + e) * 32 + (lane & 7) * 4]) = uc;
}

// ---------------- final: per-head MFMA GEMM [20000 x 32] = AVh[h] (20000x192) @ Bh[h] ----------------
__global__ __launch_bounds__(256) void final_kernel(
    const unsigned short* __restrict__ AVh, const unsigned short* __restrict__ Bh,
    float* __restrict__ out)
{
    __shared__ unsigned short As[128][200];
    __shared__ unsigned short Bs[32][200];
    const int t = threadIdx.x;
    const int w = t >> 6, lane = t & 63;
    const int l15 = lane & 15, q4 = lane >> 4;
    const int m0 = blockIdx.x * 128;
    const int h = blockIdx.y;

    #pragma unroll
    for (int it = 0; it < 12; ++it) {
        int lin = t + it * 256;           // 3072 chunks of 8 shorts
        int row = lin / 24, c8 = (lin - row * 24) * 8;
        int node = m0 + row;
        bfrag a = {};
        if (node < N_NODES)
            a = *reinterpret_cast<const bfrag*>(AVh + ((size_t)h * N_NODES + node) * 192 + c8);
        *reinterpret_cast<bfrag*>(&As[row][c8]) = a;
    }
    #pragma unroll
    for (int it = 0; it < 3; ++it) {
        int lin = t + it * 256;           // 768 chunks
        int row = lin / 24, c8 = (lin - row * 24) * 8;
        bfrag bfr = *reinterpret_cast<const bfrag*>(Bh + (size_t)(h * 32 + row) * 192 + c8);
        *reinterpret_cast<bfrag*>(&Bs[row][c8]) = bfr;
    }
    __syncthreads();

    f32x4 acc[2][2] = {};
    #pragma unroll
    for (int kk = 0; kk < 6; ++kk) {
        bfrag af[2], bf[2];
        #pragma unroll
        for (int i = 0; i < 2; ++i) {
            af[i] = *reinterpret_cast<const bfrag*>(&As[w * 32 + i * 16 + l15][kk * 32 + q4 * 8]);
            bf[i] = *reinterpret_cast<const bfrag*>(&Bs[i * 16 + l15][kk * 32 + q4 * 8]);
        }
        #pragma unroll
        for (int mi = 0; mi < 2; ++mi)
            #pragma unroll
            for (int ni = 0; ni < 2; ++ni)
                acc[mi][ni] = __builtin_amdgcn_mfma_f32_16x16x32_bf16(
                    bf[ni], af[mi], acc[mi][ni], 0, 0, 0);
    }
    #pragma unroll
    for (int mi = 0; mi < 2; ++mi) {
        int node = m0 + w * 32 + mi * 16 + l15;
        if (node >= N_NODES) continue;
        #pragma unroll
        for (int ni = 0; ni < 2; ++ni) {
            int col = h * 32 + ni * 16 + q4 * 4;
            float4 r;
            r.x = fmaxf(acc[mi][ni][0] * (1.f / 3.f), 0.f);
            r.y = fmaxf(acc[mi][ni][1] * (1.f / 3.f), 0.f);
            r.z = fmaxf(acc[mi][ni][2] * (1.f / 3.f), 0.f);
            r.w = fmaxf(acc[mi][ni][3] * (1.f / 3.f), 0.f);
            *reinterpret_cast<float4*>(&out[(size_t)node * 256 + col]) = r;
        }
    }
}

extern "C" void kernel_launch(void* const* d_in, const int* in_sizes, int n_in,
                              void* d_out, int out_size, void* d_ws, size_t ws_size,
                              hipStream_t stream) {
    const float* x        = (const float*)d_in[0];
    const float* Wk       = (const float*)d_in[1];
    const float* bk       = (const float*)d_in[2];
    const float* Wq       = (const float*)d_in[3];
    const float* bq       = (const float*)d_in[4];
    const float* Wv       = (const float*)d_in[5];
    const float* bv       = (const float*)d_in[6];
    const float* pri      = (const float*)d_in[7];
    const float* msg      = (const float*)d_in[8];
    const float* pri_cau  = (const float*)d_in[9];
    const float* msg_cau  = (const float*)d_in[10];
    const float* comb_pri = (const float*)d_in[11];
    const float* cau_filt = (const float*)d_in[12];
    const float* time_emb = (const float*)d_in[13];
    const int*   cau_type = (const int*)d_in[14];
    const int*   src      = (const int*)d_in[15];
    const int*   dst      = (const int*)d_in[16];
    float* out = (float*)d_out;

    unsigned short* qb      = (unsigned short*)d_ws;             // NF
    unsigned short* kv      = qb + NF;                           // 2*NF (k|v interleaved 4-chunks)
    unsigned short* qcf_all = kv + 2 * NF;                       // 3*NF
    unsigned short* Xb      = qcf_all + 3 * NF;                  // NF
    unsigned short* AVh     = Xb + NF;                           // 8*20000*192
    unsigned short* Wt_all  = AVh + (size_t)8 * N_NODES * 192;   // 6*65536
    unsigned short* Bh      = Wt_all + 6 * 65536;                // 8*32*192
    float* bias_all         = (float*)(Bh + 8 * 32 * 192);       // 6*256
    int* counts  = (int*)(bias_all + 6 * 256);                   // 60000
    int* buckets = counts + 3 * N_NODES;                         // 60000*BKT
    size_t need = (size_t)((char*)(buckets + (size_t)3 * N_NODES * BKT) - (char*)d_ws);
    if (ws_size < need) return;

    prep_kernel<<<dim3(ZB + XB + CB + 6 + BHB), dim3(256), 0, stream>>>(
        x, Wq, Wk, Wv, bq, bk, bv, cau_filt, msg, msg_cau, comb_pri,
        counts, Xb, Wt_all, bias_all, Bh);
    gemm_scatter_kernel<<<dim3((N_NODES + 127) / 128, 2, 7), dim3(256), 0, stream>>>(
        Xb, Wt_all, bias_all, src, dst, cau_type, qb, kv, qcf_all, counts, buckets);
    attn_kernel<<<dim3(N_NODES), dim3(192), 0, stream>>>(
        qb, qcf_all, kv, buckets, counts, pri, pri_cau, time_emb, AVh);
    final_kernel<<<dim3(157, 8), dim3(256), 0, stream>>>(AVh, Bh, out);
}